// Round 9
// baseline (127.866 us; speedup 1.0000x reference)
//
#include <hip/hip_runtime.h>

#define BB 64
#define CC 3
#define HH 224
#define WW 224
#define KK 37
#define PP 18
#define PLANE (HH*WW)

#define BM 64            // output rows per block (2 stripes of 32); 224 = 3*64 + 32
#define BROWS 100        // BM + KK - 1 (full band)
#define BSTR 264         // shorts; conflict-free; rows 16B-aligned
#define FRAGS 2560       // shorts per (slab,ky): 5q x 2hi x 32ln x 8j
#define NTT (8*CC*KK)    // 888 fragment blocks
#define TT_BYTES ((size_t)NTT * FRAGS * sizeof(unsigned short))  // ~4.55 MB

typedef __attribute__((ext_vector_type(8)))  __bf16 bf16x8;
typedef __attribute__((ext_vector_type(16))) float  f32x16;

__device__ __forceinline__ unsigned short f2bf(float f) {
    unsigned int u = __float_as_uint(f);
    return (unsigned short)((u + 0x7FFFu + ((u >> 16) & 1u)) >> 16);   // RNE
}
__device__ __forceinline__ float bf2f(unsigned short h) {
    return __uint_as_float(((unsigned int)h) << 16);
}

// frag[s][q][hi][ln][j] = w[ky][16q+8hi+j - ln] (0 outside band); also writes targets
__global__ __launch_bounds__(256) void build_frags(
    const float* __restrict__ psf, unsigned short* __restrict__ tt,
    const int* __restrict__ targets, float* __restrict__ tout)
{
    const int s = blockIdx.x;                // (p*3+c)*37 + ky
    const int ky = s % KK;
    const int pc = s / KK;
    const int p = pc / CC, c = pc - (pc / CC) * CC;
    const float* wrow = psf + (size_t)(((p*5 + 2)*CC + c)*KK + ky) * KK;
    unsigned short* dst = tt + (size_t)s * FRAGS;
    for (int e = threadIdx.x; e < FRAGS; e += 256) {
        int j = e & 7, ln = (e >> 3) & 31, hi = (e >> 8) & 1, q = e >> 9;
        int kx = 16*q + 8*hi + j - ln;
        dst[e] = (kx >= 0 && kx < KK) ? f2bf(wrow[kx]) : (unsigned short)0;
    }
    if (s == 0 && threadIdx.x < BB) tout[threadIdx.x] = (float)targets[threadIdx.x];
}

__device__ __forceinline__ void load_bq_ws(bf16x8 (&bq)[5], const unsigned short* kybase) {
    #pragma unroll
    for (int q = 0; q < 5; ++q)
        bq[q] = *(const bf16x8*)(kybase + q*512);
}

__device__ __forceinline__ void load_bq_fb(bf16x8 (&bq)[5], const unsigned short* s_w16,
                                           int ky, int hi, int ln) {
    #pragma unroll
    for (int q = 0; q < 5; ++q) {
        union { bf16x8 v; unsigned short s[8]; } u;
        #pragma unroll
        for (int j = 0; j < 8; ++j) {
            int kx = 16*q + 8*hi + j - ln;
            u.s[j] = (kx >= 0 && kx < KK) ? s_w16[ky*40 + kx] : (unsigned short)0;
        }
        bq[q] = u.v;
    }
}

// prefetch all A chunks of one band row into named regs (static indices only)
template<int NC>
__device__ __forceinline__ void load_af(bf16x8 (&af)[11], const unsigned short* rp) {
    #pragma unroll
    for (int c = 0; c < NC; ++c)
        af[c] = *(const bf16x8*)(rp + 16*c);
}

#define MFMA4(T,AF,Q) T = __builtin_amdgcn_mfma_f32_32x32x16_bf16(af[AF], bq[Q], T, 0, 0, 0)

// NT=4: tiles at cols +0,32,64,96 (chunks 0-10); NT=3: +0,32,64 (chunks 0-8).
// Tile t uses chunks 2t..2t+4 with bq[c-2t]. Interleaved for 3-4-way acc ILP.
template<int NT>
__device__ __forceinline__ void compute_ky(const bf16x8 (&af)[11], const bf16x8 (&bq)[5],
                                           f32x16& A0, f32x16& A1, f32x16& A2, f32x16& A3)
{
    MFMA4(A0,0,0);
    MFMA4(A0,1,1);
    MFMA4(A0,2,2); MFMA4(A1,2,0);
    MFMA4(A0,3,3); MFMA4(A1,3,1);
    MFMA4(A0,4,4); MFMA4(A1,4,2); MFMA4(A2,4,0);
    MFMA4(A1,5,3); MFMA4(A2,5,1);
    MFMA4(A1,6,4); MFMA4(A2,6,2); if constexpr (NT == 4) { MFMA4(A3,6,0); }
    MFMA4(A2,7,3); if constexpr (NT == 4) { MFMA4(A3,7,1); }
    MFMA4(A2,8,4); if constexpr (NT == 4) { MFMA4(A3,8,2); MFMA4(A3,9,3); MFMA4(A3,10,4); }
}

#define SP1 __builtin_amdgcn_s_setprio(1)
#define SP0 __builtin_amdgcn_s_setprio(0)

// af+bq for ky+1 are issued BEFORE ky's MFMA cluster -> latency hidden under MFMAs.
template<bool FROM_WS, int NT>
__device__ __forceinline__ void kloop(
    const unsigned short* base,              // &s_band[(32wr+ln)*BSTR + 128xh + 8hi]
    const unsigned short* fb,                // ws frag base (incl. lane off) or s_w16
    int hi, int ln,
    f32x16& A0, f32x16& A1, f32x16& A2, f32x16& A3)
{
    constexpr int NC = (NT == 4) ? 11 : 9;
    bf16x8 afA[11], afB[11], bqA[5], bqB[5];
    load_af<NC>(afA, base);
    if constexpr (FROM_WS) load_bq_ws(bqA, fb); else load_bq_fb(bqA, fb, 0, hi, ln);
    for (int ky = 0; ky < KK; ky += 2) {
        if (ky + 1 < KK) {
            load_af<NC>(afB, base + (ky + 1)*BSTR);
            if constexpr (FROM_WS) load_bq_ws(bqB, fb + (size_t)(ky + 1)*FRAGS);
            else load_bq_fb(bqB, fb, ky + 1, hi, ln);
        }
        SP1; compute_ky<NT>(afA, bqA, A0, A1, A2, A3); SP0;
        if (ky + 1 >= KK) break;
        if (ky + 2 < KK) {
            load_af<NC>(afA, base + (ky + 2)*BSTR);
            if constexpr (FROM_WS) load_bq_ws(bqA, fb + (size_t)(ky + 2)*FRAGS);
            else load_bq_fb(bqA, fb, ky + 2, hi, ln);
        }
        SP1; compute_ky<NT>(afB, bqB, A0, A1, A2, A3); SP0;
    }
}

template<bool FROM_WS>
__global__ __launch_bounds__(256, 3) void optics_mfma(
    const float* __restrict__ batch,
    const float* __restrict__ psf,
    const unsigned short* __restrict__ tt,
    const int* __restrict__ params,
    const float* __restrict__ weights,
    float* __restrict__ out)
{
    __shared__ __align__(16) unsigned short s_band[BROWS*BSTR + 16]; // 52,832 B -> 3 blk/CU
    __shared__ __align__(16) unsigned short s_w16[FROM_WS ? 8 : KK*40];

    const int tid = threadIdx.x;
    const int yband = blockIdx.x;            // 0..3
    const int plane = blockIdx.y;            // 0..191
    const int b = plane / CC, c = plane - b*CC;
    const int y0 = yband * BM;
    const int rows = (HH - y0 < BM) ? (HH - y0) : BM;   // 64,64,64,32
    const int brows = rows + KK - 1;
    const int p = params[b];

    // --- stage reflect-padded band, fp32 -> bf16 ---
    const float* src = batch + (size_t)plane * PLANE;
    // interior: gx 0..223 as 56 aligned float4 groups -> cols 18..241
    for (int i = tid; i < brows*56; i += 256) {
        int r = i / 56, g = i - r*56;
        int gy = y0 + r - PP;
        gy = gy < 0 ? -gy : (gy >= HH ? 2*HH - 2 - gy : gy);
        float4 v = *(const float4*)&src[gy*WW + 4*g];
        unsigned int lo  = f2bf(v.x) | ((unsigned int)f2bf(v.y) << 16);
        unsigned int hi2 = f2bf(v.z) | ((unsigned int)f2bf(v.w) << 16);
        unsigned int* d = (unsigned int*)&s_band[r*BSTR + PP + 4*g];
        d[0] = lo; d[1] = hi2;
    }
    // edges: cols 0..17 (left reflect), 242..259 (right reflect), 260..263 (zero)
    for (int i = tid; i < brows*40; i += 256) {
        int r = i / 40, e = i - r*40;
        int col = e < PP ? e : (224 + e);     // e=18..39 -> col 242..263
        unsigned short v = 0;
        if (col < 260) {
            int gy = y0 + r - PP;
            gy = gy < 0 ? -gy : (gy >= HH ? 2*HH - 2 - gy : gy);
            int gx = col - PP;
            gx = gx < 0 ? -gx : (gx >= WW ? 2*WW - 2 - gx : gx);
            v = f2bf(src[gy*WW + gx]);
        }
        s_band[r*BSTR + col] = v;
    }
    if (tid < 16) s_band[brows*BSTR + tid] = 0;   // guard row for chunk overrun (B=0 there)
    if constexpr (!FROM_WS) {
        const float* ksrc = psf + (size_t)((p*5 + 2)*CC + c) * (KK*KK);
        for (int i = tid; i < KK*KK; i += 256) {
            int ky_ = i / KK, kx_ = i - ky_*KK;
            s_w16[ky_*40 + kx_] = f2bf(ksrc[i]);
        }
    }
    __syncthreads();     // the ONLY barrier

    const int lane = tid & 63;
    const int wid  = tid >> 6;               // 0..3
    const int wr   = wid >> 1;               // stripe 0/1 (rows 0-31 / 32-63)
    const int xh   = wid & 1;                // x-half: tiles 0-3 / 4-6
    const int ln   = lane & 31;
    const int hi   = lane >> 5;
    const bool active = (wr == 0) || (rows > 32);

    if (active) {
        const unsigned short* fb;
        if constexpr (FROM_WS)
            fb = tt + (size_t)((p*CC + c)*KK)*FRAGS + hi*256 + ln*8;
        else
            fb = s_w16;
        const unsigned short* base = &s_band[(32*wr + ln)*BSTR + 128*xh + 8*hi];

        f32x16 A0 = {0,0,0,0, 0,0,0,0, 0,0,0,0, 0,0,0,0};
        f32x16 A1 = A0, A2 = A0, A3 = A0;

        if (xh == 0) kloop<FROM_WS, 4>(base, fb, hi, ln, A0, A1, A2, A3);
        else         kloop<FROM_WS, 3>(base, fb, hi, ln, A0, A1, A2, A3);

        // --- epilogue: blend + store (m74 D layout) ---
        const float wt = weights[b];
        const float w1 = 1.0f - wt;
        float* dst = out + (size_t)plane * PLANE;
#define EPI(ACC, GT) { \
        _Pragma("unroll") \
        for (int r = 0; r < 16; ++r) { \
            const int rowL = (r & 3) + 8*(r >> 2) + 4*hi; \
            const int yo = y0 + 32*wr + rowL; \
            const int xo = 32*(GT) + ln; \
            const float orig = bf2f(s_band[(32*wr + rowL + PP)*BSTR + xo + PP]); \
            dst[yo*WW + xo] = w1*orig + wt*ACC[r]; \
        } }
        if (xh == 0) { EPI(A0, 0) EPI(A1, 1) EPI(A2, 2) EPI(A3, 3) }
        else         { EPI(A0, 4) EPI(A1, 5) EPI(A2, 6) }
#undef EPI
    }
}

__global__ void copy_targets(const int* __restrict__ t, float* __restrict__ out) {
    int i = threadIdx.x;
    if (i < BB) out[i] = (float)t[i];
}

extern "C" void kernel_launch(void* const* d_in, const int* in_sizes, int n_in,
                              void* d_out, int out_size, void* d_ws, size_t ws_size,
                              hipStream_t stream) {
    const float* batch   = (const float*)d_in[0];
    const int*   targets = (const int*)d_in[1];
    const float* psf     = (const float*)d_in[2];
    const int*   params  = (const int*)d_in[3];
    const float* weights = (const float*)d_in[4];
    float* out = (float*)d_out;
    unsigned short* tt = (unsigned short*)d_ws;

    dim3 grid((HH + BM - 1) / BM, BB*CC);     // 4 x 192 = 768 = 256 CU x 3 (exact fit)

    if (ws_size >= TT_BYTES) {
        build_frags<<<NTT, 256, 0, stream>>>(psf, tt, targets,
                                             out + (size_t)BB*CC*PLANE);
        optics_mfma<true><<<grid, 256, 0, stream>>>(batch, psf, tt, params, weights, out);
    } else {
        optics_mfma<false><<<grid, 256, 0, stream>>>(batch, psf, tt, params, weights, out);
        copy_targets<<<1, 64, 0, stream>>>(targets, out + (size_t)BB*CC*PLANE);
    }
}

// Round 10
// 84.970 us; speedup vs baseline: 1.5048x; 1.5048x over previous
//
#include <hip/hip_runtime.h>

#define BB 64
#define CC 3
#define HH 224
#define WW 224
#define KK 37
#define PP 18
#define PLANE (HH*WW)

#define BM 32            // output rows per block; 224 = 7*32, no tail band
#define BROWS 68         // BM + KK - 1
#define BSTR 264         // shorts; conflict-free; rows 16B-aligned
#define FRAGS 2560       // shorts per (slab,ky): 5q x 2hi x 32ln x 8j
#define NTT (8*CC*KK)    // 888 fragment blocks
#define TT_BYTES ((size_t)NTT * FRAGS * sizeof(unsigned short))  // ~4.55 MB

typedef __attribute__((ext_vector_type(8)))  __bf16 bf16x8;
typedef __attribute__((ext_vector_type(16))) float  f32x16;

__device__ __forceinline__ unsigned short f2bf(float f) {
    unsigned int u = __float_as_uint(f);
    return (unsigned short)((u + 0x7FFFu + ((u >> 16) & 1u)) >> 16);   // RNE
}
__device__ __forceinline__ float bf2f(unsigned short h) {
    return __uint_as_float(((unsigned int)h) << 16);
}

// frag[s][q][hi][ln][j] = w[ky][16q+8hi+j - ln] (0 outside band); also writes targets
__global__ __launch_bounds__(256) void build_frags(
    const float* __restrict__ psf, unsigned short* __restrict__ tt,
    const int* __restrict__ targets, float* __restrict__ tout)
{
    const int s = blockIdx.x;                // (p*3+c)*37 + ky
    const int ky = s % KK;
    const int pc = s / KK;
    const int p = pc / CC, c = pc - (pc / CC) * CC;
    const float* wrow = psf + (size_t)(((p*5 + 2)*CC + c)*KK + ky) * KK;
    unsigned short* dst = tt + (size_t)s * FRAGS;
    for (int e = threadIdx.x; e < FRAGS; e += 256) {
        int j = e & 7, ln = (e >> 3) & 31, hi = (e >> 8) & 1, q = e >> 9;
        int kx = 16*q + 8*hi + j - ln;
        dst[e] = (kx >= 0 && kx < KK) ? f2bf(wrow[kx]) : (unsigned short)0;
    }
    if (s == 0 && threadIdx.x < BB) tout[threadIdx.x] = (float)targets[threadIdx.x];
}

__device__ __forceinline__ void load_bq_ws(bf16x8 (&bq)[5], const unsigned short* kybase) {
    #pragma unroll
    for (int q = 0; q < 5; ++q)
        bq[q] = *(const bf16x8*)(kybase + q*512);
}

__device__ __forceinline__ void load_bq_fb(bf16x8 (&bq)[5], const unsigned short* s_w16,
                                           int ky, int hi, int ln) {
    #pragma unroll
    for (int q = 0; q < 5; ++q) {
        union { bf16x8 v; unsigned short s[8]; } u;
        #pragma unroll
        for (int j = 0; j < 8; ++j) {
            int kx = 16*q + 8*hi + j - ln;
            u.s[j] = (kx >= 0 && kx < KK) ? s_w16[ky*40 + kx] : (unsigned short)0;
        }
        bq[q] = u.v;
    }
}

// prefetch one band row's A chunks into named regs (static indices only)
template<int NC>
__device__ __forceinline__ void load_af(bf16x8 (&af)[NC], const unsigned short* rp) {
    #pragma unroll
    for (int c = 0; c < NC; ++c)
        af[c] = *(const bf16x8*)(rp + 16*c);
}

#define MFMA4(T,AF,Q) T = __builtin_amdgcn_mfma_f32_32x32x16_bf16(af[AF], bq[Q], T, 0, 0, 0)

// NT=2: tiles at +0 (chunks 0-4, bq[c]) and +32 (chunks 2-6, bq[c-2]). NT=1: +0 only.
template<int NT, int NC>
__device__ __forceinline__ void compute_ky(const bf16x8 (&af)[NC], const bf16x8 (&bq)[5],
                                           f32x16& A0, f32x16& A1)
{
    if constexpr (NT == 2) {
        MFMA4(A0,0,0);
        MFMA4(A0,1,1);
        MFMA4(A0,2,2); MFMA4(A1,2,0);
        MFMA4(A0,3,3); MFMA4(A1,3,1);
        MFMA4(A0,4,4); MFMA4(A1,4,2);
        MFMA4(A1,5,3);
        MFMA4(A1,6,4);
    } else {
        MFMA4(A0,0,0);
        MFMA4(A0,1,1);
        MFMA4(A0,2,2);
        MFMA4(A0,3,3);
        MFMA4(A0,4,4);
    }
}

#define SP1 __builtin_amdgcn_s_setprio(1)
#define SP0 __builtin_amdgcn_s_setprio(0)

// af+bq for ky+1 fully loaded to regs BEFORE ky's MFMA cluster (latency hidden).
// Register budget: afA+afB 56 + bqA+bqB 40 + acc 32 + addr ~20 = ~150 < 170 (3/SIMD).
template<bool FROM_WS, int NT>
__device__ __forceinline__ void kloop(
    const unsigned short* base,              // &s_band[ln*BSTR + 64w + 8hi]
    const unsigned short* fb,                // ws frag base (incl. lane off) or s_w16
    int hi, int ln, f32x16& A0, f32x16& A1)
{
    constexpr int NC = (NT == 2) ? 7 : 5;
    bf16x8 afA[NC], afB[NC], bqA[5], bqB[5];
    load_af<NC>(afA, base);
    if constexpr (FROM_WS) load_bq_ws(bqA, fb); else load_bq_fb(bqA, fb, 0, hi, ln);
    for (int ky = 0; ky < KK; ky += 2) {
        if (ky + 1 < KK) {
            load_af<NC>(afB, base + (ky + 1)*BSTR);
            if constexpr (FROM_WS) load_bq_ws(bqB, fb + (size_t)(ky + 1)*FRAGS);
            else load_bq_fb(bqB, fb, ky + 1, hi, ln);
        }
        SP1; compute_ky<NT, NC>(afA, bqA, A0, A1); SP0;
        if (ky + 1 >= KK) break;
        if (ky + 2 < KK) {
            load_af<NC>(afA, base + (ky + 2)*BSTR);
            if constexpr (FROM_WS) load_bq_ws(bqA, fb + (size_t)(ky + 2)*FRAGS);
            else load_bq_fb(bqA, fb, ky + 2, hi, ln);
        }
        SP1; compute_ky<NT, NC>(afB, bqB, A0, A1); SP0;
    }
}

template<bool FROM_WS>
__global__ __launch_bounds__(256, 3) void optics_mfma(
    const float* __restrict__ batch,
    const float* __restrict__ psf,
    const unsigned short* __restrict__ tt,
    const int* __restrict__ params,
    const float* __restrict__ weights,
    float* __restrict__ out)
{
    __shared__ __align__(16) unsigned short s_band[BROWS*BSTR + 16]; // 35,936 B
    __shared__ __align__(16) unsigned short s_w16[FROM_WS ? 8 : KK*40];

    const int tid = threadIdx.x;
    const int yband = blockIdx.x;            // 0..6
    const int plane = blockIdx.y;            // 0..191
    const int b = plane / CC, c = plane - b*CC;
    const int y0 = yband * BM;
    const int p = params[b];

    // --- stage reflect-padded band, fp32 -> bf16 ---
    const float* src = batch + (size_t)plane * PLANE;
    // interior: gx 0..223 as 56 aligned float4 groups -> cols 18..241
    for (int i = tid; i < BROWS*56; i += 256) {
        int r = i / 56, g = i - r*56;
        int gy = y0 + r - PP;
        gy = gy < 0 ? -gy : (gy >= HH ? 2*HH - 2 - gy : gy);
        float4 v = *(const float4*)&src[gy*WW + 4*g];
        unsigned int lo  = f2bf(v.x) | ((unsigned int)f2bf(v.y) << 16);
        unsigned int hi2 = f2bf(v.z) | ((unsigned int)f2bf(v.w) << 16);
        unsigned int* d = (unsigned int*)&s_band[r*BSTR + PP + 4*g];
        d[0] = lo; d[1] = hi2;
    }
    // edges: cols 0..17 (left reflect), 242..259 (right reflect), 260..263 (zero)
    for (int i = tid; i < BROWS*40; i += 256) {
        int r = i / 40, e = i - r*40;
        int col = e < PP ? e : (224 + e);     // e=18..39 -> col 242..263
        unsigned short v = 0;
        if (col < 260) {
            int gy = y0 + r - PP;
            gy = gy < 0 ? -gy : (gy >= HH ? 2*HH - 2 - gy : gy);
            int gx = col - PP;
            gx = gx < 0 ? -gx : (gx >= WW ? 2*WW - 2 - gx : gx);
            v = f2bf(src[gy*WW + gx]);
        }
        s_band[r*BSTR + col] = v;
    }
    if (tid < 16) s_band[BROWS*BSTR + tid] = 0;   // guard tail (tile-6 overrun, B=0 there)
    if constexpr (!FROM_WS) {
        const float* ksrc = psf + (size_t)((p*5 + 2)*CC + c) * (KK*KK);
        for (int i = tid; i < KK*KK; i += 256) {
            int ky_ = i / KK, kx_ = i - ky_*KK;
            s_w16[ky_*40 + kx_] = f2bf(ksrc[i]);
        }
    }
    __syncthreads();     // the ONLY barrier

    const int lane = tid & 63;
    const int w    = tid >> 6;               // wave 0..3: tiles {0,1}{2,3}{4,5}{6}
    const int ln   = lane & 31;
    const int hi   = lane >> 5;

    const unsigned short* fb;
    if constexpr (FROM_WS)
        fb = tt + (size_t)((p*CC + c)*KK)*FRAGS + hi*256 + ln*8;
    else
        fb = s_w16;
    const unsigned short* base = &s_band[ln*BSTR + 64*w + 8*hi];

    f32x16 A0 = {0,0,0,0, 0,0,0,0, 0,0,0,0, 0,0,0,0};
    f32x16 A1 = A0;

    if (w < 3) kloop<FROM_WS, 2>(base, fb, hi, ln, A0, A1);
    else       kloop<FROM_WS, 1>(base, fb, hi, ln, A0, A1);

    // --- epilogue: blend + store (m74 D layout) ---
    const float wt = weights[b];
    const float w1 = 1.0f - wt;
    float* dst = out + (size_t)plane * PLANE;
#define EPI(ACC, GT) { \
    _Pragma("unroll") \
    for (int r = 0; r < 16; ++r) { \
        const int rowL = (r & 3) + 8*(r >> 2) + 4*hi; \
        const int yo = y0 + rowL; \
        const int xo = 32*(GT) + ln; \
        const float orig = bf2f(s_band[(rowL + PP)*BSTR + xo + PP]); \
        dst[yo*WW + xo] = w1*orig + wt*ACC[r]; \
    } }
    EPI(A0, 2*w)
    if (w < 3) EPI(A1, 2*w + 1)
#undef EPI
}

__global__ void copy_targets(const int* __restrict__ t, float* __restrict__ out) {
    int i = threadIdx.x;
    if (i < BB) out[i] = (float)t[i];
}

extern "C" void kernel_launch(void* const* d_in, const int* in_sizes, int n_in,
                              void* d_out, int out_size, void* d_ws, size_t ws_size,
                              hipStream_t stream) {
    const float* batch   = (const float*)d_in[0];
    const int*   targets = (const int*)d_in[1];
    const float* psf     = (const float*)d_in[2];
    const int*   params  = (const int*)d_in[3];
    const float* weights = (const float*)d_in[4];
    float* out = (float*)d_out;
    unsigned short* tt = (unsigned short*)d_ws;

    dim3 grid(HH / BM, BB*CC);                // 7 x 192 = 1344 blocks

    if (ws_size >= TT_BYTES) {
        build_frags<<<NTT, 256, 0, stream>>>(psf, tt, targets,
                                             out + (size_t)BB*CC*PLANE);
        optics_mfma<true><<<grid, 256, 0, stream>>>(batch, psf, tt, params, weights, out);
    } else {
        optics_mfma<false><<<grid, 256, 0, stream>>>(batch, psf, tt, params, weights, out);
        copy_targets<<<1, 64, 0, stream>>>(targets, out + (size_t)BB*CC*PLANE);
    }
}

// Round 11
// 82.360 us; speedup vs baseline: 1.5525x; 1.0317x over previous
//
#include <hip/hip_runtime.h>

#define BB 64
#define CC 3
#define HH 224
#define WW 224
#define KK 37
#define PP 18
#define PLANE (HH*WW)

#define BM 32            // output rows per block; 224 = 7*32, no tail band
#define BROWS 68         // BM + KK - 1
#define BSTR 264         // shorts; conflict-free; rows 16B-aligned
#define FRAGS 2560       // shorts per (slab,ky): 5q x 2hi x 32ln x 8j
#define NTT (8*CC*KK)    // 888 fragment blocks
#define TT_BYTES ((size_t)NTT * FRAGS * sizeof(unsigned short))  // ~4.55 MB

typedef __attribute__((ext_vector_type(8)))  __bf16 bf16x8;
typedef __attribute__((ext_vector_type(4)))  unsigned int u32x4;
typedef __attribute__((ext_vector_type(16))) float  f32x16;

__device__ __forceinline__ unsigned short f2bf(float f) {
    unsigned int u = __float_as_uint(f);
    return (unsigned short)((u + 0x7FFFu + ((u >> 16) & 1u)) >> 16);   // RNE
}
__device__ __forceinline__ float bf2f(unsigned short h) {
    return __uint_as_float(((unsigned int)h) << 16);
}

// frag[s][q][hi][ln][j] = w[ky][16q+8hi+j - ln] (0 outside band); also writes targets
__global__ __launch_bounds__(256) void build_frags(
    const float* __restrict__ psf, unsigned short* __restrict__ tt,
    const int* __restrict__ targets, float* __restrict__ tout)
{
    const int s = blockIdx.x;                // (p*3+c)*37 + ky
    const int ky = s % KK;
    const int pc = s / KK;
    const int p = pc / CC, c = pc - (pc / CC) * CC;
    const float* wrow = psf + (size_t)(((p*5 + 2)*CC + c)*KK + ky) * KK;
    unsigned short* dst = tt + (size_t)s * FRAGS;
    for (int e = threadIdx.x; e < FRAGS; e += 256) {
        int j = e & 7, ln = (e >> 3) & 31, hi = (e >> 8) & 1, q = e >> 9;
        int kx = 16*q + 8*hi + j - ln;
        dst[e] = (kx >= 0 && kx < KK) ? f2bf(wrow[kx]) : (unsigned short)0;
    }
    if (s == 0 && threadIdx.x < BB) tout[threadIdx.x] = (float)targets[threadIdx.x];
}

__device__ __forceinline__ void load_bq_ws(u32x4 (&bq)[5], const unsigned short* kybase) {
    #pragma unroll
    for (int q = 0; q < 5; ++q)
        bq[q] = *(const u32x4*)(kybase + q*512);
}

__device__ __forceinline__ void load_bq_fb(u32x4 (&bq)[5], const unsigned short* s_w16,
                                           int ky, int hi, int ln) {
    #pragma unroll
    for (int q = 0; q < 5; ++q) {
        union { u32x4 v; unsigned short s[8]; } u;
        #pragma unroll
        for (int j = 0; j < 8; ++j) {
            int kx = 16*q + 8*hi + j - ln;
            u.s[j] = (kx >= 0 && kx < KK) ? s_w16[ky*40 + kx] : (unsigned short)0;
        }
        bq[q] = u.v;
    }
}

#define MFMA_(T,Q) T = __builtin_amdgcn_mfma_f32_32x32x16_bf16( \
    __builtin_bit_cast(bf16x8, af), __builtin_bit_cast(bf16x8, bq[Q]), T, 0, 0, 0)

// NT=2: tiles at +0 (chunks 0-4, bq[c]) and +32 (chunks 2-6, bq[c-2]). NT=1: +0 only.
// A chunks JIT from LDS (compiler emits counted lgkmcnt); bq already in regs.
template<int NT>
__device__ __forceinline__ void compute_ky(const unsigned short* rp, const u32x4 (&bq)[5],
                                           f32x16& A0, f32x16& A1)
{
    u32x4 af;
#define LDC(c) af = *(const u32x4*)(rp + 16*(c))
    if constexpr (NT == 2) {
        LDC(0); MFMA_(A0,0);
        LDC(1); MFMA_(A0,1);
        LDC(2); MFMA_(A0,2); MFMA_(A1,0);
        LDC(3); MFMA_(A0,3); MFMA_(A1,1);
        LDC(4); MFMA_(A0,4); MFMA_(A1,2);
        LDC(5); MFMA_(A1,3);
        LDC(6); MFMA_(A1,4);
    } else {
        LDC(0); MFMA_(A0,0);
        LDC(1); MFMA_(A0,1);
        LDC(2); MFMA_(A0,2);
        LDC(3); MFMA_(A0,3);
        LDC(4); MFMA_(A0,4);
    }
#undef LDC
}

#define SP1 __builtin_amdgcn_s_setprio(1)
#define SP0 __builtin_amdgcn_s_setprio(0)
#define SBAR __builtin_amdgcn_sched_barrier(0)

// Staggered ky loop (start 9*w, wrap mod 37): waves de-lockstep so one wave's
// load burst overlaps another's MFMA cluster. bq(ky+1) issue is pinned BEFORE
// compute(ky) by sched_barrier(0) -> one full cluster of vmem latency cover,
// with completion waited (counted vmcnt) only at first use in the next cluster.
template<bool FROM_WS, int NT>
__device__ __forceinline__ void kloop(
    const unsigned short* base,              // &s_band[ln*BSTR + 64w + 8hi]
    const unsigned short* fb,                // ws frag base (incl. lane off) or s_w16
    int off, int hi, int ln, f32x16& A0, f32x16& A1)
{
    u32x4 bqA[5], bqB[5];
    int kyA = off;
    if constexpr (FROM_WS) load_bq_ws(bqA, fb + (size_t)kyA*FRAGS);
    else load_bq_fb(bqA, fb, kyA, hi, ln);
    #pragma unroll 3
    for (int t = 0; t < KK - 1; t += 2) {
        int kyB = kyA + 1; if (kyB == KK) kyB = 0;
        if constexpr (FROM_WS) load_bq_ws(bqB, fb + (size_t)kyB*FRAGS);
        else load_bq_fb(bqB, fb, kyB, hi, ln);
        SBAR;
        SP1; compute_ky<NT>(base + kyA*BSTR, bqA, A0, A1); SP0;
        int kyN = kyB + 1; if (kyN == KK) kyN = 0;
        if constexpr (FROM_WS) load_bq_ws(bqA, fb + (size_t)kyN*FRAGS);
        else load_bq_fb(bqA, fb, kyN, hi, ln);
        SBAR;
        SP1; compute_ky<NT>(base + kyB*BSTR, bqB, A0, A1); SP0;
        kyA = kyN;
    }
    SP1; compute_ky<NT>(base + kyA*BSTR, bqA, A0, A1); SP0;   // 37th (odd tail)
}

template<bool FROM_WS>
__global__ __launch_bounds__(256, 4) void optics_mfma(
    const float* __restrict__ batch,
    const float* __restrict__ psf,
    const unsigned short* __restrict__ tt,
    const int* __restrict__ params,
    const float* __restrict__ weights,
    float* __restrict__ out)
{
    __shared__ __align__(16) unsigned short s_band[BROWS*BSTR + 16]; // 35,936 B
    __shared__ __align__(16) unsigned short s_w16[FROM_WS ? 8 : KK*40];

    const int tid = threadIdx.x;
    const int yband = blockIdx.x;            // 0..6
    const int plane = blockIdx.y;            // 0..191
    const int b = plane / CC, c = plane - b*CC;
    const int y0 = yband * BM;
    const int p = params[b];

    // --- stage reflect-padded band, fp32 -> bf16 ---
    const float* src = batch + (size_t)plane * PLANE;
    // interior: gx 0..223 as 56 aligned float4 groups -> cols 18..241
    for (int i = tid; i < BROWS*56; i += 256) {
        int r = i / 56, g = i - r*56;
        int gy = y0 + r - PP;
        gy = gy < 0 ? -gy : (gy >= HH ? 2*HH - 2 - gy : gy);
        float4 v = *(const float4*)&src[gy*WW + 4*g];
        unsigned int lo  = f2bf(v.x) | ((unsigned int)f2bf(v.y) << 16);
        unsigned int hi2 = f2bf(v.z) | ((unsigned int)f2bf(v.w) << 16);
        unsigned int* d = (unsigned int*)&s_band[r*BSTR + PP + 4*g];
        d[0] = lo; d[1] = hi2;
    }
    // edges: cols 0..17 (left reflect), 242..259 (right reflect), 260..263 (zero)
    for (int i = tid; i < BROWS*40; i += 256) {
        int r = i / 40, e = i - r*40;
        int col = e < PP ? e : (224 + e);     // e=18..39 -> col 242..263
        unsigned short v = 0;
        if (col < 260) {
            int gy = y0 + r - PP;
            gy = gy < 0 ? -gy : (gy >= HH ? 2*HH - 2 - gy : gy);
            int gx = col - PP;
            gx = gx < 0 ? -gx : (gx >= WW ? 2*WW - 2 - gx : gx);
            v = f2bf(src[gy*WW + gx]);
        }
        s_band[r*BSTR + col] = v;
    }
    if (tid < 16) s_band[BROWS*BSTR + tid] = 0;   // guard tail (tile-6 overrun, B=0 there)
    if constexpr (!FROM_WS) {
        const float* ksrc = psf + (size_t)((p*5 + 2)*CC + c) * (KK*KK);
        for (int i = tid; i < KK*KK; i += 256) {
            int ky_ = i / KK, kx_ = i - ky_*KK;
            s_w16[ky_*40 + kx_] = f2bf(ksrc[i]);
        }
    }
    __syncthreads();     // the ONLY barrier

    const int lane = tid & 63;
    const int w    = tid >> 6;               // wave 0..3: tiles {0,1}{2,3}{4,5}{6}
    const int ln   = lane & 31;
    const int hi   = lane >> 5;
    const int off  = 9 * w;                  // ky stagger: 0,9,18,27

    const unsigned short* fb;
    if constexpr (FROM_WS)
        fb = tt + (size_t)((p*CC + c)*KK)*FRAGS + hi*256 + ln*8;
    else
        fb = s_w16;
    const unsigned short* base = &s_band[ln*BSTR + 64*w + 8*hi];

    f32x16 A0 = {0,0,0,0, 0,0,0,0, 0,0,0,0, 0,0,0,0};
    f32x16 A1 = A0;

    if (w < 3) kloop<FROM_WS, 2>(base, fb, off, hi, ln, A0, A1);
    else       kloop<FROM_WS, 1>(base, fb, off, hi, ln, A0, A1);

    // --- epilogue: blend + store (m74 D layout) ---
    const float wt = weights[b];
    const float w1 = 1.0f - wt;
    float* dst = out + (size_t)plane * PLANE;
#define EPI(ACC, GT) { \
    _Pragma("unroll") \
    for (int r = 0; r < 16; ++r) { \
        const int rowL = (r & 3) + 8*(r >> 2) + 4*hi; \
        const int yo = y0 + rowL; \
        const int xo = 32*(GT) + ln; \
        const float orig = bf2f(s_band[(rowL + PP)*BSTR + xo + PP]); \
        dst[yo*WW + xo] = w1*orig + wt*ACC[r]; \
    } }
    EPI(A0, 2*w)
    if (w < 3) EPI(A1, 2*w + 1)
#undef EPI
}

__global__ void copy_targets(const int* __restrict__ t, float* __restrict__ out) {
    int i = threadIdx.x;
    if (i < BB) out[i] = (float)t[i];
}

extern "C" void kernel_launch(void* const* d_in, const int* in_sizes, int n_in,
                              void* d_out, int out_size, void* d_ws, size_t ws_size,
                              hipStream_t stream) {
    const float* batch   = (const float*)d_in[0];
    const int*   targets = (const int*)d_in[1];
    const float* psf     = (const float*)d_in[2];
    const int*   params  = (const int*)d_in[3];
    const float* weights = (const float*)d_in[4];
    float* out = (float*)d_out;
    unsigned short* tt = (unsigned short*)d_ws;

    dim3 grid(HH / BM, BB*CC);                // 7 x 192 = 1344 blocks

    if (ws_size >= TT_BYTES) {
        build_frags<<<NTT, 256, 0, stream>>>(psf, tt, targets,
                                             out + (size_t)BB*CC*PLANE);
        optics_mfma<true><<<grid, 256, 0, stream>>>(batch, psf, tt, params, weights, out);
    } else {
        optics_mfma<false><<<grid, 256, 0, stream>>>(batch, psf, tt, params, weights, out);
        copy_targets<<<1, 64, 0, stream>>>(targets, out + (size_t)BB*CC*PLANE);
    }
}

// Round 12
// 78.492 us; speedup vs baseline: 1.6290x; 1.0493x over previous
//
#include <hip/hip_runtime.h>

#define BB 64
#define CC 3
#define HH 224
#define WW 224
#define KK 37
#define PP 18
#define PLANE (HH*WW)

#define BM 32            // output rows per block; 224 = 7*32, no tail band
#define BROWS 68         // BM + KK - 1
#define BSTR 264         // shorts; conflict-free; rows 16B-aligned
#define FRAGS 2560       // shorts per (slab,ky): 5q x 2hi x 32ln x 8j
#define NTT (8*CC*KK)    // 888 fragment blocks
#define TT_BYTES ((size_t)NTT * FRAGS * sizeof(unsigned short))  // ~4.55 MB

typedef __attribute__((ext_vector_type(8)))  __bf16 bf16x8;
typedef __attribute__((ext_vector_type(4)))  unsigned int u32x4;
typedef __attribute__((ext_vector_type(16))) float  f32x16;

__device__ __forceinline__ unsigned short f2bf(float f) {
    unsigned int u = __float_as_uint(f);
    return (unsigned short)((u + 0x7FFFu + ((u >> 16) & 1u)) >> 16);   // RNE
}
__device__ __forceinline__ float bf2f(unsigned short h) {
    return __uint_as_float(((unsigned int)h) << 16);
}

// frag[s][q][hi][ln][j] = w[ky][16q+8hi+j - ln] (0 outside band); also writes targets
__global__ __launch_bounds__(256) void build_frags(
    const float* __restrict__ psf, unsigned short* __restrict__ tt,
    const int* __restrict__ targets, float* __restrict__ tout)
{
    const int s = blockIdx.x;                // (p*3+c)*37 + ky
    const int ky = s % KK;
    const int pc = s / KK;
    const int p = pc / CC, c = pc - (pc / CC) * CC;
    const float* wrow = psf + (size_t)(((p*5 + 2)*CC + c)*KK + ky) * KK;
    unsigned short* dst = tt + (size_t)s * FRAGS;
    for (int e = threadIdx.x; e < FRAGS; e += 256) {
        int j = e & 7, ln = (e >> 3) & 31, hi = (e >> 8) & 1, q = e >> 9;
        int kx = 16*q + 8*hi + j - ln;
        dst[e] = (kx >= 0 && kx < KK) ? f2bf(wrow[kx]) : (unsigned short)0;
    }
    if (s == 0 && threadIdx.x < BB) tout[threadIdx.x] = (float)targets[threadIdx.x];
}

// 5 volatile asm loads: compiler cannot sink/merge/unbuffer these. No implicit wait.
__device__ __forceinline__ void load_bq_asm(u32x4 (&bq)[5], const unsigned short* kybase) {
    const unsigned short* p = kybase + 1024;   // +2048B center; q*1024B-2048 in 13-bit imm
    asm volatile("global_load_dwordx4 %0, %1, off offset:-2048" : "=v"(bq[0]) : "v"(p));
    asm volatile("global_load_dwordx4 %0, %1, off offset:-1024" : "=v"(bq[1]) : "v"(p));
    asm volatile("global_load_dwordx4 %0, %1, off"              : "=v"(bq[2]) : "v"(p));
    asm volatile("global_load_dwordx4 %0, %1, off offset:1024"  : "=v"(bq[3]) : "v"(p));
    asm volatile("global_load_dwordx4 %0, %1, off offset:2048"  : "=v"(bq[4]) : "v"(p));
}

__device__ __forceinline__ void load_bq_fb(u32x4 (&bq)[5], const unsigned short* s_w16,
                                           int ky, int hi, int ln) {
    #pragma unroll
    for (int q = 0; q < 5; ++q) {
        union { u32x4 v; unsigned short s[8]; } u;
        #pragma unroll
        for (int j = 0; j < 8; ++j) {
            int kx = 16*q + 8*hi + j - ln;
            u.s[j] = (kx >= 0 && kx < KK) ? s_w16[ky*40 + kx] : (unsigned short)0;
        }
        bq[q] = u.v;
    }
}

#define MFMA_(T,Q) T = __builtin_amdgcn_mfma_f32_32x32x16_bf16( \
    __builtin_bit_cast(bf16x8, af), __builtin_bit_cast(bf16x8, bq[Q]), T, 0, 0, 0)

// NT=2: tiles at +0 (chunks 0-4, bq[c]) and +32 (chunks 2-6, bq[c-2]). NT=1: +0 only.
// af chunks JIT from LDS (compiler emits counted lgkmcnt); bq already in regs.
template<int NT>
__device__ __forceinline__ void compute_ky(const unsigned short* rp, const u32x4 (&bq)[5],
                                           f32x16& A0, f32x16& A1)
{
    u32x4 af;
#define LDC(c) af = *(const u32x4*)(rp + 16*(c))
    if constexpr (NT == 2) {
        LDC(0); MFMA_(A0,0);
        LDC(1); MFMA_(A0,1);
        LDC(2); MFMA_(A0,2); MFMA_(A1,0);
        LDC(3); MFMA_(A0,3); MFMA_(A1,1);
        LDC(4); MFMA_(A0,4); MFMA_(A1,2);
        LDC(5); MFMA_(A1,3);
        LDC(6); MFMA_(A1,4);
    } else {
        LDC(0); MFMA_(A0,0);
        LDC(1); MFMA_(A0,1);
        LDC(2); MFMA_(A0,2);
        LDC(3); MFMA_(A0,3);
        LDC(4); MFMA_(A0,4);
    }
#undef LDC
}

#define SP1 __builtin_amdgcn_s_setprio(1)
#define SP0 __builtin_amdgcn_s_setprio(0)
// counted wait: oldest 5 of 10 outstanding bq loads done; fence MFMA below (rule #18)
#define VMWAIT(N) do { asm volatile("s_waitcnt vmcnt(" #N ")" ::: "memory"); \
                       __builtin_amdgcn_sched_barrier(0); } while (0)

// Hand-built 2-deep pipeline with counted vmcnt: 10 loads in flight steady-state.
// Timeline per phase: [wait oldest 5][compute ~400cy][issue next 5] -> each load
// gets a full compute phase of latency cover; compiler cannot undo (asm loads).
template<int NT>
__device__ __forceinline__ void kloop_ws(
    const unsigned short* base, const unsigned short* fb,
    f32x16& A0, f32x16& A1)
{
    u32x4 bqA[5], bqB[5];
    load_bq_asm(bqA, fb);                        // ky 0
    load_bq_asm(bqB, fb + FRAGS);                // ky 1
    for (int ky = 0; ky < KK - 2; ky += 2) {
        VMWAIT(5);                               // bqA(ky) ready, bqB in flight
        SP1; compute_ky<NT>(base + ky*BSTR, bqA, A0, A1); SP0;
        load_bq_asm(bqA, fb + (size_t)(ky + 2)*FRAGS);
        VMWAIT(5);                               // bqB(ky+1) ready, bqA in flight
        SP1; compute_ky<NT>(base + (ky + 1)*BSTR, bqB, A0, A1); SP0;
        if (ky + 3 < KK)
            load_bq_asm(bqB, fb + (size_t)(ky + 3)*FRAGS);
    }
    VMWAIT(0);                                   // bqA(36) ready
    SP1; compute_ky<NT>(base + (KK - 1)*BSTR, bqA, A0, A1); SP0;
}

template<int NT>
__device__ __forceinline__ void kloop_fb(
    const unsigned short* base, const unsigned short* s_w16,
    int hi, int ln, f32x16& A0, f32x16& A1)
{
    u32x4 bq[5];
    for (int ky = 0; ky < KK; ++ky) {
        load_bq_fb(bq, s_w16, ky, hi, ln);
        compute_ky<NT>(base + ky*BSTR, bq, A0, A1);
    }
}

template<bool FROM_WS>
__global__ __launch_bounds__(256, 4) void optics_mfma(
    const float* __restrict__ batch,
    const float* __restrict__ psf,
    const unsigned short* __restrict__ tt,
    const int* __restrict__ params,
    const float* __restrict__ weights,
    float* __restrict__ out)
{
    __shared__ __align__(16) unsigned short s_band[BROWS*BSTR + 16]; // 35,936 B
    __shared__ __align__(16) unsigned short s_w16[FROM_WS ? 8 : KK*40];

    const int tid = threadIdx.x;
    const int yband = blockIdx.x;            // 0..6
    const int plane = blockIdx.y;            // 0..191
    const int b = plane / CC, c = plane - b*CC;
    const int y0 = yband * BM;
    const int p = params[b];

    // --- stage reflect-padded band, fp32 -> bf16 ---
    const float* src = batch + (size_t)plane * PLANE;
    // interior: gx 0..223 as 56 aligned float4 groups -> cols 18..241
    for (int i = tid; i < BROWS*56; i += 256) {
        int r = i / 56, g = i - r*56;
        int gy = y0 + r - PP;
        gy = gy < 0 ? -gy : (gy >= HH ? 2*HH - 2 - gy : gy);
        float4 v = *(const float4*)&src[gy*WW + 4*g];
        unsigned int lo  = f2bf(v.x) | ((unsigned int)f2bf(v.y) << 16);
        unsigned int hi2 = f2bf(v.z) | ((unsigned int)f2bf(v.w) << 16);
        unsigned int* d = (unsigned int*)&s_band[r*BSTR + PP + 4*g];
        d[0] = lo; d[1] = hi2;
    }
    // edges: cols 0..17 (left reflect), 242..259 (right reflect), 260..263 (zero)
    for (int i = tid; i < BROWS*40; i += 256) {
        int r = i / 40, e = i - r*40;
        int col = e < PP ? e : (224 + e);     // e=18..39 -> col 242..263
        unsigned short v = 0;
        if (col < 260) {
            int gy = y0 + r - PP;
            gy = gy < 0 ? -gy : (gy >= HH ? 2*HH - 2 - gy : gy);
            int gx = col - PP;
            gx = gx < 0 ? -gx : (gx >= WW ? 2*WW - 2 - gx : gx);
            v = f2bf(src[gy*WW + gx]);
        }
        s_band[r*BSTR + col] = v;
    }
    if (tid < 16) s_band[BROWS*BSTR + tid] = 0;   // guard tail (tile-6 overrun, B=0 there)
    if constexpr (!FROM_WS) {
        const float* ksrc = psf + (size_t)((p*5 + 2)*CC + c) * (KK*KK);
        for (int i = tid; i < KK*KK; i += 256) {
            int ky_ = i / KK, kx_ = i - ky_*KK;
            s_w16[ky_*40 + kx_] = f2bf(ksrc[i]);
        }
    }
    __syncthreads();     // drains vmcnt to 0 -> clean counter base for kloop_ws

    const int lane = tid & 63;
    const int w    = tid >> 6;               // wave 0..3: tiles {0,1}{2,3}{4,5}{6}
    const int ln   = lane & 31;
    const int hi   = lane >> 5;

    const unsigned short* base = &s_band[ln*BSTR + 64*w + 8*hi];

    f32x16 A0 = {0,0,0,0, 0,0,0,0, 0,0,0,0, 0,0,0,0};
    f32x16 A1 = A0;

    if constexpr (FROM_WS) {
        const unsigned short* fb = tt + (size_t)((p*CC + c)*KK)*FRAGS + hi*256 + ln*8;
        if (w < 3) kloop_ws<2>(base, fb, A0, A1);
        else       kloop_ws<1>(base, fb, A0, A1);
    } else {
        if (w < 3) kloop_fb<2>(base, s_w16, hi, ln, A0, A1);
        else       kloop_fb<1>(base, s_w16, hi, ln, A0, A1);
    }

    // --- epilogue: blend + store (m74 D layout) ---
    const float wt = weights[b];
    const float w1 = 1.0f - wt;
    float* dst = out + (size_t)plane * PLANE;
#define EPI(ACC, GT) { \
    _Pragma("unroll") \
    for (int r = 0; r < 16; ++r) { \
        const int rowL = (r & 3) + 8*(r >> 2) + 4*hi; \
        const int yo = y0 + rowL; \
        const int xo = 32*(GT) + ln; \
        const float orig = bf2f(s_band[(rowL + PP)*BSTR + xo + PP]); \
        dst[yo*WW + xo] = w1*orig + wt*ACC[r]; \
    } }
    EPI(A0, 2*w)
    if (w < 3) EPI(A1, 2*w + 1)
#undef EPI
}

__global__ void copy_targets(const int* __restrict__ t, float* __restrict__ out) {
    int i = threadIdx.x;
    if (i < BB) out[i] = (float)t[i];
}

extern "C" void kernel_launch(void* const* d_in, const int* in_sizes, int n_in,
                              void* d_out, int out_size, void* d_ws, size_t ws_size,
                              hipStream_t stream) {
    const float* batch   = (const float*)d_in[0];
    const int*   targets = (const int*)d_in[1];
    const float* psf     = (const float*)d_in[2];
    const int*   params  = (const int*)d_in[3];
    const float* weights = (const float*)d_in[4];
    float* out = (float*)d_out;
    unsigned short* tt = (unsigned short*)d_ws;

    dim3 grid(HH / BM, BB*CC);                // 7 x 192 = 1344 blocks

    if (ws_size >= TT_BYTES) {
        build_frags<<<NTT, 256, 0, stream>>>(psf, tt, targets,
                                             out + (size_t)BB*CC*PLANE);
        optics_mfma<true><<<grid, 256, 0, stream>>>(batch, psf, tt, params, weights, out);
    } else {
        optics_mfma<false><<<grid, 256, 0, stream>>>(batch, psf, tt, params, weights, out);
        copy_targets<<<1, 64, 0, stream>>>(targets, out + (size_t)BB*CC*PLANE);
    }
}

// Round 13
// 68.210 us; speedup vs baseline: 1.8746x; 1.1507x over previous
//
#include <hip/hip_runtime.h>

#define BB 64
#define CC 3
#define HH 224
#define WW 224
#define KK 37
#define PP 18
#define PLANE (HH*WW)

#define BM 64            // output rows per block (2 stripes); 224 = 3*64 + 32
#define BROWS 100        // BM + KK - 1
#define BSTR 264         // shorts; conflict-free; rows 16B-aligned
#define FRAGS 2560       // shorts per (slab,ky): 5q x 2hi x 32ln x 8j
#define NTT (8*CC*KK)    // 888 fragment blocks
#define TT_BYTES ((size_t)NTT * FRAGS * sizeof(unsigned short))  // ~4.55 MB
#define NBLK 768         // 4 ybands x 192 planes = 3 per CU exactly

typedef __attribute__((ext_vector_type(8)))  __bf16 bf16x8;
typedef __attribute__((ext_vector_type(4)))  unsigned int u32x4;
typedef __attribute__((ext_vector_type(16))) float  f32x16;

__device__ __forceinline__ unsigned short f2bf(float f) {
    unsigned int u = __float_as_uint(f);
    return (unsigned short)((u + 0x7FFFu + ((u >> 16) & 1u)) >> 16);   // RNE
}
__device__ __forceinline__ float bf2f(unsigned short h) {
    return __uint_as_float(((unsigned int)h) << 16);
}

// frag[s][q][hi][ln][j] = w[ky][16q+8hi+j - ln] (0 outside band); also writes targets
__global__ __launch_bounds__(256) void build_frags(
    const float* __restrict__ psf, unsigned short* __restrict__ tt,
    const int* __restrict__ targets, float* __restrict__ tout)
{
    const int s = blockIdx.x;                // (p*3+c)*37 + ky
    const int ky = s % KK;
    const int pc = s / KK;
    const int p = pc / CC, c = pc - (pc / CC) * CC;
    const float* wrow = psf + (size_t)(((p*5 + 2)*CC + c)*KK + ky) * KK;
    unsigned short* dst = tt + (size_t)s * FRAGS;
    for (int e = threadIdx.x; e < FRAGS; e += 256) {
        int j = e & 7, ln = (e >> 3) & 31, hi = (e >> 8) & 1, q = e >> 9;
        int kx = 16*q + 8*hi + j - ln;
        dst[e] = (kx >= 0 && kx < KK) ? f2bf(wrow[kx]) : (unsigned short)0;
    }
    if (s == 0 && threadIdx.x < BB) tout[threadIdx.x] = (float)targets[threadIdx.x];
}

// 5 volatile asm loads: compiler cannot sink/merge these; completion waited manually.
__device__ __forceinline__ void load_bq_asm(u32x4 (&bq)[5], const unsigned short* kybase) {
    const unsigned short* p = kybase + 1024;   // center; q*1024B-2048 fits 13-bit imm
    asm volatile("global_load_dwordx4 %0, %1, off offset:-2048" : "=v"(bq[0]) : "v"(p));
    asm volatile("global_load_dwordx4 %0, %1, off offset:-1024" : "=v"(bq[1]) : "v"(p));
    asm volatile("global_load_dwordx4 %0, %1, off"              : "=v"(bq[2]) : "v"(p));
    asm volatile("global_load_dwordx4 %0, %1, off offset:1024"  : "=v"(bq[3]) : "v"(p));
    asm volatile("global_load_dwordx4 %0, %1, off offset:2048"  : "=v"(bq[4]) : "v"(p));
}

__device__ __forceinline__ void load_bq_fb(u32x4 (&bq)[5], const unsigned short* s_w16,
                                           int ky, int hi, int ln) {
    #pragma unroll
    for (int q = 0; q < 5; ++q) {
        union { u32x4 v; unsigned short s[8]; } u;
        #pragma unroll
        for (int j = 0; j < 8; ++j) {
            int kx = 16*q + 8*hi + j - ln;
            u.s[j] = (kx >= 0 && kx < KK) ? s_w16[ky*40 + kx] : (unsigned short)0;
        }
        bq[q] = u.v;
    }
}

#define MFMA_(T,Q) T = __builtin_amdgcn_mfma_f32_32x32x16_bf16( \
    __builtin_bit_cast(bf16x8, af), __builtin_bit_cast(bf16x8, bq[Q]), T, 0, 0, 0)

// NT=4: tiles at +0,32,64,96 (chunks 0-10); NT=3: +0,32,64 (chunks 0-8).
// Tile t uses chunks 2t..2t+4 with bq[c-2t]. af chunks JIT from LDS.
template<int NT>
__device__ __forceinline__ void compute_ky(const unsigned short* rp, const u32x4 (&bq)[5],
                                           f32x16& A0, f32x16& A1, f32x16& A2, f32x16& A3)
{
    u32x4 af;
#define LDC(c) af = *(const u32x4*)(rp + 16*(c))
    LDC(0);  MFMA_(A0,0);
    LDC(1);  MFMA_(A0,1);
    LDC(2);  MFMA_(A0,2); MFMA_(A1,0);
    LDC(3);  MFMA_(A0,3); MFMA_(A1,1);
    LDC(4);  MFMA_(A0,4); MFMA_(A1,2); MFMA_(A2,0);
    LDC(5);  MFMA_(A1,3); MFMA_(A2,1);
    if constexpr (NT == 4) {
        LDC(6);  MFMA_(A1,4); MFMA_(A2,2); MFMA_(A3,0);
        LDC(7);  MFMA_(A2,3); MFMA_(A3,1);
        LDC(8);  MFMA_(A2,4); MFMA_(A3,2);
        LDC(9);  MFMA_(A3,3);
        LDC(10); MFMA_(A3,4);
    } else {
        LDC(6);  MFMA_(A1,4); MFMA_(A2,2);
        LDC(7);  MFMA_(A2,3);
        LDC(8);  MFMA_(A2,4);
    }
#undef LDC
}

#define SP1 __builtin_amdgcn_s_setprio(1)
#define SP0 __builtin_amdgcn_s_setprio(0)
#define VMWAIT(N) do { asm volatile("s_waitcnt vmcnt(" #N ")" ::: "memory"); \
                       __builtin_amdgcn_sched_barrier(0); } while (0)

// 2-deep asm pipeline, 10 loads in flight, counted vmcnt(5) (R12-proven machinery).
// Each 5KB bq fill now feeds 20/15 MFMAs (was 10/5) -> bq traffic per plane -1.75x.
template<int NT>
__device__ __forceinline__ void kloop_ws(
    const unsigned short* base, const unsigned short* fb,
    f32x16& A0, f32x16& A1, f32x16& A2, f32x16& A3)
{
    u32x4 bqA[5], bqB[5];
    load_bq_asm(bqA, fb);                        // ky 0
    load_bq_asm(bqB, fb + FRAGS);                // ky 1
    for (int ky = 0; ky < KK - 2; ky += 2) {
        VMWAIT(5);
        SP1; compute_ky<NT>(base + ky*BSTR, bqA, A0, A1, A2, A3); SP0;
        load_bq_asm(bqA, fb + (size_t)(ky + 2)*FRAGS);
        VMWAIT(5);
        SP1; compute_ky<NT>(base + (ky + 1)*BSTR, bqB, A0, A1, A2, A3); SP0;
        if (ky + 3 < KK)
            load_bq_asm(bqB, fb + (size_t)(ky + 3)*FRAGS);
    }
    VMWAIT(0);
    SP1; compute_ky<NT>(base + (KK - 1)*BSTR, bqA, A0, A1, A2, A3); SP0;
}

template<int NT>
__device__ __forceinline__ void kloop_fb(
    const unsigned short* base, const unsigned short* s_w16,
    int hi, int ln, f32x16& A0, f32x16& A1, f32x16& A2, f32x16& A3)
{
    u32x4 bq[5];
    for (int ky = 0; ky < KK; ++ky) {
        load_bq_fb(bq, s_w16, ky, hi, ln);
        compute_ky<NT>(base + ky*BSTR, bq, A0, A1, A2, A3);
    }
}

template<bool FROM_WS>
__global__ __launch_bounds__(256, 3) void optics_mfma(
    const float* __restrict__ batch,
    const float* __restrict__ psf,
    const unsigned short* __restrict__ tt,
    const int* __restrict__ params,
    const float* __restrict__ weights,
    float* __restrict__ out)
{
    __shared__ __align__(16) unsigned short s_band[BROWS*BSTR + 16]; // 52,832 B -> 3/CU
    __shared__ __align__(16) unsigned short s_w16[FROM_WS ? 8 : KK*40];

    const int tid = threadIdx.x;
    // XCD-chunked bijective swizzle: XCD j gets items [96j, 96j+96) = 24 planes,
    // so each XCD's L2 sees a few hot 185KB tt slab streams instead of all 4.55MB.
    const int n = blockIdx.x;                 // 0..767
    const int item = (n & 7) * (NBLK / 8) + (n >> 3);
    const int plane = item >> 2;              // 0..191
    const int yband = item & 3;               // 0..3
    const int b = plane / CC, c = plane - b*CC;
    const int y0 = yband * BM;
    const int rows = (HH - y0 < BM) ? (HH - y0) : BM;   // 64,64,64,32
    const int brows = rows + KK - 1;
    const int p = params[b];

    // --- stage reflect-padded band, fp32 -> bf16 ---
    const float* src = batch + (size_t)plane * PLANE;
    // interior: gx 0..223 as 56 aligned float4 groups -> cols 18..241
    for (int i = tid; i < brows*56; i += 256) {
        int r = i / 56, g = i - r*56;
        int gy = y0 + r - PP;
        gy = gy < 0 ? -gy : (gy >= HH ? 2*HH - 2 - gy : gy);
        float4 v = *(const float4*)&src[gy*WW + 4*g];
        unsigned int lo  = f2bf(v.x) | ((unsigned int)f2bf(v.y) << 16);
        unsigned int hi2 = f2bf(v.z) | ((unsigned int)f2bf(v.w) << 16);
        unsigned int* d = (unsigned int*)&s_band[r*BSTR + PP + 4*g];
        d[0] = lo; d[1] = hi2;
    }
    // edges: cols 0..17 (left reflect), 242..259 (right reflect), 260..263 (zero)
    for (int i = tid; i < brows*40; i += 256) {
        int r = i / 40, e = i - r*40;
        int col = e < PP ? e : (224 + e);     // e=18..39 -> col 242..263
        unsigned short v = 0;
        if (col < 260) {
            int gy = y0 + r - PP;
            gy = gy < 0 ? -gy : (gy >= HH ? 2*HH - 2 - gy : gy);
            int gx = col - PP;
            gx = gx < 0 ? -gx : (gx >= WW ? 2*WW - 2 - gx : gx);
            v = f2bf(src[gy*WW + gx]);
        }
        s_band[r*BSTR + col] = v;
    }
    if (tid < 16) s_band[brows*BSTR + tid] = 0;   // guard (last-chunk overrun, B=0 there)
    if constexpr (!FROM_WS) {
        const float* ksrc = psf + (size_t)((p*5 + 2)*CC + c) * (KK*KK);
        for (int i = tid; i < KK*KK; i += 256) {
            int ky_ = i / KK, kx_ = i - ky_*KK;
            s_w16[ky_*40 + kx_] = f2bf(ksrc[i]);
        }
    }
    __syncthreads();     // drains vmcnt -> clean counter base for kloop_ws

    const int lane = tid & 63;
    const int wid  = tid >> 6;               // 0..3
    const int wr   = wid >> 1;               // stripe 0/1 (rows 0-31 / 32-63)
    const int xh   = wid & 1;                // x-half: tiles 0-3 / 4-6
    const int ln   = lane & 31;
    const int hi   = lane >> 5;
    const bool active = (wr == 0) || (rows > 32);

    if (active) {
        const unsigned short* base = &s_band[(32*wr + ln)*BSTR + 128*xh + 8*hi];

        f32x16 A0 = {0,0,0,0, 0,0,0,0, 0,0,0,0, 0,0,0,0};
        f32x16 A1 = A0, A2 = A0, A3 = A0;

        if constexpr (FROM_WS) {
            const unsigned short* fb = tt + (size_t)((p*CC + c)*KK)*FRAGS + hi*256 + ln*8;
            if (xh == 0) kloop_ws<4>(base, fb, A0, A1, A2, A3);
            else         kloop_ws<3>(base, fb, A0, A1, A2, A3);
        } else {
            if (xh == 0) kloop_fb<4>(base, s_w16, hi, ln, A0, A1, A2, A3);
            else         kloop_fb<3>(base, s_w16, hi, ln, A0, A1, A2, A3);
        }

        // --- epilogue: blend + store (m74 D layout) ---
        const float wt = weights[b];
        const float w1 = 1.0f - wt;
        float* dst = out + (size_t)plane * PLANE;
#define EPI(ACC, GT) { \
        _Pragma("unroll") \
        for (int r = 0; r < 16; ++r) { \
            const int rowL = (r & 3) + 8*(r >> 2) + 4*hi; \
            const int yo = y0 + 32*wr + rowL; \
            const int xo = 32*(GT) + ln; \
            const float orig = bf2f(s_band[(32*wr + rowL + PP)*BSTR + xo + PP]); \
            dst[yo*WW + xo] = w1*orig + wt*ACC[r]; \
        } }
        if (xh == 0) { EPI(A0, 0) EPI(A1, 1) EPI(A2, 2) EPI(A3, 3) }
        else         { EPI(A0, 4) EPI(A1, 5) EPI(A2, 6) }
#undef EPI
    } else {
        // keep vmcnt discipline trivially satisfied (no loads were issued)
    }
}

__global__ void copy_targets(const int* __restrict__ t, float* __restrict__ out) {
    int i = threadIdx.x;
    if (i < BB) out[i] = (float)t[i];
}

extern "C" void kernel_launch(void* const* d_in, const int* in_sizes, int n_in,
                              void* d_out, int out_size, void* d_ws, size_t ws_size,
                              hipStream_t stream) {
    const float* batch   = (const float*)d_in[0];
    const int*   targets = (const int*)d_in[1];
    const float* psf     = (const float*)d_in[2];
    const int*   params  = (const int*)d_in[3];
    const float* weights = (const float*)d_in[4];
    float* out = (float*)d_out;
    unsigned short* tt = (unsigned short*)d_ws;

    if (ws_size >= TT_BYTES) {
        build_frags<<<NTT, 256, 0, stream>>>(psf, tt, targets,
                                             out + (size_t)BB*CC*PLANE);
        optics_mfma<true><<<NBLK, 256, 0, stream>>>(batch, psf, tt, params, weights, out);
    } else {
        optics_mfma<false><<<NBLK, 256, 0, stream>>>(batch, psf, tt, params, weights, out);
        copy_targets<<<1, 64, 0, stream>>>(targets, out + (size_t)BB*CC*PLANE);
    }
}